// Round 3
// baseline (2378.526 us; speedup 1.0000x reference)
//
#include <hip/hip_runtime.h>

#define NN 1024
#define NW 32   // 32-bit words per row bitset

// ---- Kernel A: edge float data -> hard-decision bit matrix E[NN][NW] ----
__global__ void edge_bits_kernel(const float* __restrict__ ep,
                                 const float* __restrict__ ge,
                                 unsigned* __restrict__ E) {
    int idx = blockIdx.x * blockDim.x + threadIdx.x;   // element (i*NN + j)
    float  p = ep[idx];
    float2 g = reinterpret_cast<const float2*>(ge)[idx];
    bool hard = (p + g.x) > ((1.0f - p) + g.y);        // exact IEEE f32
    unsigned long long m = __ballot(hard);
    int lane = threadIdx.x & 63;
    if ((lane & 31) == 0)
        E[idx >> 5] = (unsigned)(m >> (lane & 32));
}

// ---- Kernel B: serial BFS on bitsets; 2 barriers/iter; all state in LDS/regs ----
__global__ __launch_bounds__(1024) void dag_bfs_bits(
    const float* __restrict__ root_probs,
    const float* __restrict__ g_roots,
    const unsigned* __restrict__ E,
    unsigned* __restrict__ dagbits_g)
{
    extern __shared__ unsigned smem[];
    unsigned* dag = smem;                                        // NN*NW words (128 KiB)
    unsigned long long* masks = (unsigned long long*)(dag + NN * NW); // 16 u64
    unsigned* ancI = (unsigned*)(masks + 16);                    // 2*NW (double buffer)
    int* queue = (int*)(ancI + 2 * NW);                          // NN ints

    const int tid  = threadIdx.x;
    const int lane = tid & 63;
    const int wid  = tid >> 6;
    const int      myw   = tid >> 5;
    const unsigned mybit = 1u << (tid & 31);

    // zero dag bits (unprocessed rows must stay 0)
    #pragma unroll
    for (int k = 0; k < NW; ++k) dag[tid + k * NN] = 0u;

    // own ancestor row in registers (statically indexed only)
    unsigned ancreg[NW];
    #pragma unroll
    for (int k = 0; k < NW; ++k) ancreg[k] = (k == myw) ? mybit : 0u;

    float  rp = root_probs[tid];
    float2 gr = reinterpret_cast<const float2*>(g_roots)[tid];
    bool root    = (rp + gr.x) > ((1.0f - rp) + gr.y);
    bool notroot = !root;
    bool inq     = root;
    bool processed = false;

    // ---- seed: roots in ascending order; pick first node; publish its row ----
    unsigned long long m0 = __ballot(root);
    if (lane == 0) masks[wid] = m0;
    __syncthreads();
    int head = 0, tail = 0, off0 = 0, ni = -1;
    int lp0 = __popcll(m0 & ((1ULL << lane) - 1ULL));
    #pragma unroll
    for (int w = 0; w < 16; ++w) {
        unsigned long long mw = masks[w];
        int c = __popcll(mw);
        if (w < wid) off0 += c;
        tail += c;
        if (ni < 0 && mw) ni = w * 64 + (__ffsll((long long)mw) - 1);
    }
    if (root) queue[off0 + lp0] = tid;
    int p = 0;
    unsigned eword = 0;
    if (tid == ni) {
        #pragma unroll
        for (int k = 0; k < NW; ++k) ancI[k] = ancreg[k];
    }
    if (tail > 0) eword = E[ni * NW + myw];   // uniform ni; L2-resident after A
    __syncthreads();

    int i = ni;
    while (head < tail) {
        // ---- Phase 1: hit test + ballots ----
        const unsigned* aI = ancI + p * NW;
        bool abit = (aI[myw] & mybit) != 0;
        bool hit  = ((eword & mybit) != 0) && notroot && !abit;

        unsigned long long hm = __ballot(hit);
        if ((lane & 31) == 0) dag[i * NW + (tid >> 5)] = (unsigned)(hm >> (lane & 32));

        bool newf = hit && !inq;
        inq |= newf;
        unsigned long long nm = __ballot(newf);
        if (lane == 0) masks[wid] = nm;

        // speculative read of the next old queue entry (stable if head+1 < tail)
        int qnext = queue[(head + 1 < tail) ? (head + 1) : 0];
        __syncthreads();                      // masks ready

        // ---- Phase 2: scan, enqueue, pick next node, publish its row ----
        int lp = __popcll(nm & ((1ULL << lane) - 1ULL));
        int off = 0, tot = 0, firstnew = -1;
        #pragma unroll
        for (int w = 0; w < 16; ++w) {
            unsigned long long mw = masks[w];
            int c = __popcll(mw);
            if (w < wid) off += c;
            tot += c;
            if (firstnew < 0 && mw) firstnew = w * 64 + (__ffsll((long long)mw) - 1);
        }

        // anc[j] |= anc[i] for hit j (only matters pre-processing)
        if (hit && !processed) {
            #pragma unroll
            for (int k = 0; k < NW; ++k) ancreg[k] |= aI[k];
        }
        if (tid == i) processed = true;      // self-hit impossible (abit has self)

        if (newf) queue[tail + off + lp] = tid;  // ascending-j append

        int newhead = head + 1, newtail = tail + tot;
        if (newhead >= newtail) { break; }       // uniform decision across block

        int nexti = (newhead < tail) ? qnext : firstnew;
        if (tid == nexti) {
            #pragma unroll
            for (int k = 0; k < NW; ++k) ancI[(p ^ 1) * NW + k] = ancreg[k];
        }
        eword = E[nexti * NW + myw];             // issue now; consumed after barrier
        __syncthreads();                          // publish/enqueue visible

        head = newhead; tail = newtail; i = nexti; p ^= 1;
    }

    // ---- flush dag bits to global (coalesced) ----
    __syncthreads();
    #pragma unroll
    for (int k = 0; k < NW; ++k) dagbits_g[tid + k * NN] = dag[tid + k * NN];
}

// ---- Kernel C: dag bits -> f32 output ----
__global__ void expand_kernel(const unsigned* __restrict__ dagbits,
                              float4* __restrict__ out) {
    int idx = blockIdx.x * blockDim.x + threadIdx.x;  // one float4 (4 bits)
    unsigned w = dagbits[idx >> 3];
    int b = (idx & 7) * 4;
    float4 o;
    o.x = (w >> (b + 0)) & 1 ? 1.0f : 0.0f;
    o.y = (w >> (b + 1)) & 1 ? 1.0f : 0.0f;
    o.z = (w >> (b + 2)) & 1 ? 1.0f : 0.0f;
    o.w = (w >> (b + 3)) & 1 ? 1.0f : 0.0f;
    out[idx] = o;
}

extern "C" void kernel_launch(void* const* d_in, const int* in_sizes, int n_in,
                              void* d_out, int out_size, void* d_ws, size_t ws_size,
                              hipStream_t stream) {
    const float* root_probs = (const float*)d_in[0];
    const float* edge_probs = (const float*)d_in[1];
    const float* g_roots    = (const float*)d_in[2];
    const float* g_edges    = (const float*)d_in[3];

    unsigned* E       = (unsigned*)d_ws;          // 128 KiB
    unsigned* dagbits = E + NN * NW;              // 128 KiB

    edge_bits_kernel<<<NN * NN / 256, 256, 0, stream>>>(edge_probs, g_edges, E);

    size_t lds = (size_t)NN * NW * 4 + 16 * 8 + 2 * NW * 4 + NN * 4;
    hipFuncSetAttribute((const void*)dag_bfs_bits,
                        hipFuncAttributeMaxDynamicSharedMemorySize, (int)lds);
    dag_bfs_bits<<<1, NN, lds, stream>>>(root_probs, g_roots, E, dagbits);

    expand_kernel<<<NN * NN / 4 / 256, 256, 0, stream>>>(dagbits, (float4*)d_out);
}

// Round 4
// 706.008 us; speedup vs baseline: 3.3690x; 3.3690x over previous
//
#include <hip/hip_runtime.h>

#define NN 1024
#define NW 32
#define NV 8
#define INF_KEY 0x7FFFFFFFu

typedef unsigned int u32;
typedef unsigned long long u64;

// ---- A0: root hard bits ----
__global__ __launch_bounds__(1024) void root_bits_kernel(
    const float* __restrict__ rp, const float* __restrict__ gr, u32* __restrict__ rootbits)
{
    int tid = threadIdx.x;
    float p = rp[tid];
    float2 g = reinterpret_cast<const float2*>(gr)[tid];
    bool root = (p + g.x) > ((1.0f - p) + g.y);
    u64 m = __ballot(root);
    if ((tid & 31) == 0) rootbits[tid >> 5] = (u32)(m >> (tid & 32));
}

// ---- A1: edge hard bits + root dag rows written directly ----
__global__ void edge_bits_kernel(const float* __restrict__ ep, const float* __restrict__ ge,
                                 const u32* __restrict__ rootbits,
                                 u32* __restrict__ E, u32* __restrict__ dagbits)
{
    int idx = blockIdx.x * blockDim.x + threadIdx.x;
    int i = idx >> 10;
    float p = ep[idx];
    float2 g = reinterpret_cast<const float2*>(ge)[idx];
    bool hard = (p + g.x) > ((1.0f - p) + g.y);
    u64 m = __ballot(hard);
    int lane = threadIdx.x & 63;
    if ((lane & 31) == 0) {
        int w = idx >> 5;                  // flat word index
        u32 hw = (u32)(m >> (lane & 32));
        E[w] = hw;
        int jw = w & 31;                   // word within row
        u32 rootw = rootbits[jw];
        bool rooti = (rootbits[i >> 5] >> (i & 31)) & 1;
        u32 selfm = ((i >> 5) == jw) ? (1u << (i & 31)) : 0u;
        dagbits[w] = rooti ? (hw & ~rootw & ~selfm) : 0u;   // root rows final; others 0
    }
}

// ---- AT: 1024x1024 bit transpose (32x32 bit tiles via shfl) ----
__global__ void transpose_bits_kernel(const u32* __restrict__ E, u32* __restrict__ ET)
{
    int hw = (blockIdx.x * blockDim.x + threadIdx.x) >> 5;  // tile id
    int l = threadIdx.x & 31;
    int R = hw >> 5, C = hw & 31;
    u32 x = E[(R * 32 + l) * NW + C];
    #pragma unroll
    for (int s = 16; s >= 1; s >>= 1) {
        u32 mlo = (s == 16) ? 0x0000FFFFu : (s == 8) ? 0x00FF00FFu :
                  (s == 4) ? 0x0F0F0F0Fu : (s == 2) ? 0x33333333u : 0x55555555u;
        u32 y = __shfl_xor(x, s, 64);      // s<32: stays within 32-lane half
        if ((l & s) == 0) x = (x & mlo) | ((y & mlo) << s);
        else              x = (x & ~mlo) | ((y & ~mlo) >> s);
    }
    ET[(C * 32 + l) * NW + R] = x;
}

// ---- B: sequential BFS over non-root nodes only ----
__global__ __launch_bounds__(1024) void dag_bfs_bits(
    const u32* __restrict__ E, const u32* __restrict__ ET,
    const u32* __restrict__ rootbits, u32* __restrict__ dagbits)
{
    extern __shared__ u32 smem[];
    u32*  dag      = smem;                       // 131072 B
    uint4* eff     = (uint4*)(dag + NN * NW);    // 2*NV uint4
    uint4* pub     = eff + 2 * NV;               // NV uint4
    u32*  rootm    = (u32*)(pub + NV);           // 32
    u32*  rootpre  = rootm + 32;                 // 32
    int*  queue    = (int*)(rootpre + 32);       // 1024
    u32*  key      = (u32*)(queue + NN);         // 1024
    int*  wavecnt  = (int*)(key + NN);           // 16
    int*  firstcand= wavecnt + 16;               // 16
    int*  flags    = firstcand + 16;             // 4

    const int tid  = threadIdx.x;
    const int lane = tid & 63;
    const int wid  = tid >> 6;
    const int myw  = tid >> 5;
    const u32 mybit = 1u << (tid & 31);

    #pragma unroll
    for (int k = 0; k < NW; ++k) dag[tid + k * NN] = 0u;
    if (tid < 32) rootm[tid] = rootbits[tid];
    __syncthreads();
    if (tid == 0) { int s = 0;
        #pragma unroll
        for (int w = 0; w < 32; ++w) { rootpre[w] = s; s += __popc(rootm[w]); } }

    bool root = (rootm[tid >> 5] >> (tid & 31)) & 1;
    bool notroot = !root;

    // anc[tid] = {tid} U {roots hitting tid}; find first hitting root
    uint4 anc4[NV];
    int fw = -1; u32 fword = 0;
    const uint4* ET4 = (const uint4*)ET + (size_t)tid * NV;
    const uint4* rm4 = (const uint4*)rootm;
    #pragma unroll
    for (int k = 0; k < NV; ++k) {
        uint4 e = ET4[k], r = rm4[k];
        u32 a0 = notroot ? (e.x & r.x) : 0u;
        u32 a1 = notroot ? (e.y & r.y) : 0u;
        u32 a2 = notroot ? (e.z & r.z) : 0u;
        u32 a3 = notroot ? (e.w & r.w) : 0u;
        if (fw < 0 && a0) { fw = 4 * k + 0; fword = a0; }
        if (fw < 0 && a1) { fw = 4 * k + 1; fword = a1; }
        if (fw < 0 && a2) { fw = 4 * k + 2; fword = a2; }
        if (fw < 0 && a3) { fw = 4 * k + 3; fword = a3; }
        anc4[k].x = a0 | ((4 * k + 0 == myw) ? mybit : 0u);
        anc4[k].y = a1 | ((4 * k + 1 == myw) ? mybit : 0u);
        anc4[k].z = a2 | ((4 * k + 2 == myw) ? mybit : 0u);
        anc4[k].w = a3 | ((4 * k + 3 == myw) ? mybit : 0u);
    }
    bool inq = root || (fw >= 0);
    bool processed = false;
    __syncthreads();                              // rootpre ready

    // level-1 queue = nonroots sorted by (rank of first hitting root, tid)
    u32 mykey = INF_KEY;
    if (notroot && fw >= 0) {
        int t0 = fw * 32 + __ffs(fword) - 1;
        int rank = rootpre[t0 >> 5] + __popc(rootm[t0 >> 5] & ((1u << (t0 & 31)) - 1u));
        mykey = ((u32)rank << 10) | (u32)tid;
    }
    key[tid] = mykey;
    __syncthreads();
    int pos = 0, tail = 0;
    const uint4* key4 = (const uint4*)key;
    for (int q = 0; q < 256; ++q) {
        uint4 kk = key4[q];
        pos  += (kk.x < mykey) + (kk.y < mykey) + (kk.z < mykey) + (kk.w < mykey);
        tail += (kk.x != INF_KEY) + (kk.y != INF_KEY) + (kk.z != INF_KEY) + (kk.w != INF_KEY);
    }
    if (mykey != INF_KEY) queue[pos] = tid;
    __syncthreads();

    int head = 0, p = 0, i = -1;
    u32 eword = 0;
    if (tail > 0) {
        i = queue[0];
        if (tid == i) {
            #pragma unroll
            for (int k = 0; k < NV; ++k) eff[k] = anc4[k];
        }
        eword = E[i * NW + myw];
    }
    __syncthreads();

    while (head < tail) {
        // ---- P1 ----
        u32 effw = ((const u32*)(eff + p * NV))[myw];
        bool abit = (effw & mybit) != 0;
        bool hit = ((eword & mybit) != 0) && notroot && !abit;

        u64 hm = __ballot(hit);
        if ((lane & 31) == 0) dag[i * NW + (tid >> 5)] = (u32)(hm >> (lane & 32));

        bool newf = hit && !inq;
        inq |= newf;
        u64 nm = __ballot(newf);
        if (lane == 0) {
            wavecnt[wid] = (int)__popcll(nm);
            firstcand[wid] = nm ? (wid * 64 + __ffsll((long long)nm) - 1) : (int)INF_KEY;
        }
        bool have_old = (head + 1 < tail);
        int qn = -1;
        if (have_old) {
            qn = queue[head + 1];
            if (tid == qn) {
                #pragma unroll
                for (int k = 0; k < NV; ++k) pub[k] = anc4[k];
                flags[0] = hit ? 1 : 0;
            }
        }
        if (tid == i) processed = true;
        __syncthreads();                      // B1

        // ---- P2 ----
        int lp = (int)__popcll(nm & ((1ULL << lane) - 1ULL));
        int c = wavecnt[lane & 15];
        int fcv = firstcand[lane & 15];
        int incl = c;
        #pragma unroll
        for (int d = 1; d < 16; d <<= 1) {
            int u = __shfl_up(incl, d, 16);
            if ((lane & 15) >= d) incl += u;
        }
        int tot = __shfl(incl, 15, 16);
        int offw = (wid > 0) ? __shfl(incl, wid - 1, 16) : 0;
        #pragma unroll
        for (int d = 1; d < 16; d <<= 1) fcv = min(fcv, __shfl_xor(fcv, d, 16));

        if (hit && !processed) {
            const uint4* effp = eff + p * NV;
            #pragma unroll
            for (int k = 0; k < NV; ++k) {
                uint4 s = effp[k];
                anc4[k].x |= s.x; anc4[k].y |= s.y; anc4[k].z |= s.z; anc4[k].w |= s.w;
            }
        }
        if (newf) queue[tail + offw + lp] = tid;

        int newtail = tail + tot;
        head += 1;
        if (head >= newtail) break;

        int nexti = have_old ? qn : fcv;
        int fix = flags[0];
        if (tid < NV) {
            uint4 b;
            if (have_old) {
                b = pub[tid];
                if (fix) { uint4 s = eff[p * NV + tid]; b.x |= s.x; b.y |= s.y; b.z |= s.z; b.w |= s.w; }
            } else {
                b = eff[p * NV + tid];
                if ((nexti >> 7) == tid) {
                    u32 nb = 1u << (nexti & 31);
                    int comp = (nexti >> 5) & 3;
                    if (comp == 0) b.x |= nb; else if (comp == 1) b.y |= nb;
                    else if (comp == 2) b.z |= nb; else b.w |= nb;
                }
            }
            eff[(p ^ 1) * NV + tid] = b;
        }
        eword = E[nexti * NW + myw];          // prefetch; drained at B2 under P2 cover
        tail = newtail; i = nexti; p ^= 1;
        __syncthreads();                      // B2
    }

    // ---- flush non-root rows (root rows already final from A1) ----
    __syncthreads();
    const uint4* d4 = (const uint4*)dag;
    uint4* g4 = (uint4*)dagbits;
    #pragma unroll
    for (int k = 0; k < NV; ++k) {
        int q = tid + k * 1024;               // uint4 index; row = q>>3
        int r = q >> 3;
        bool rt = (rootm[r >> 5] >> (r & 31)) & 1;
        if (!rt) g4[q] = d4[q];
    }
}

// ---- C: dag bits -> f32 output ----
__global__ void expand_kernel(const u32* __restrict__ dagbits, float4* __restrict__ out)
{
    int idx = blockIdx.x * blockDim.x + threadIdx.x;
    u32 w = dagbits[idx >> 3];
    int b = (idx & 7) * 4;
    float4 o;
    o.x = (w >> (b + 0)) & 1 ? 1.0f : 0.0f;
    o.y = (w >> (b + 1)) & 1 ? 1.0f : 0.0f;
    o.z = (w >> (b + 2)) & 1 ? 1.0f : 0.0f;
    o.w = (w >> (b + 3)) & 1 ? 1.0f : 0.0f;
    out[idx] = o;
}

extern "C" void kernel_launch(void* const* d_in, const int* in_sizes, int n_in,
                              void* d_out, int out_size, void* d_ws, size_t ws_size,
                              hipStream_t stream) {
    const float* root_probs = (const float*)d_in[0];
    const float* edge_probs = (const float*)d_in[1];
    const float* g_roots    = (const float*)d_in[2];
    const float* g_edges    = (const float*)d_in[3];

    u32* E        = (u32*)d_ws;               // 128 KiB
    u32* ET       = E + NN * NW;              // 128 KiB
    u32* dagbits  = ET + NN * NW;             // 128 KiB
    u32* rootbits = dagbits + NN * NW;        // 128 B

    root_bits_kernel<<<1, NN, 0, stream>>>(root_probs, g_roots, rootbits);
    edge_bits_kernel<<<NN * NN / 256, 256, 0, stream>>>(edge_probs, g_edges, rootbits, E, dagbits);
    transpose_bits_kernel<<<128, 256, 0, stream>>>(E, ET);

    size_t lds = (size_t)NN * NW * 4 + (2 * NV + NV) * 16 + 64 * 4 + NN * 4 + NN * 4 + 36 * 4;
    hipFuncSetAttribute((const void*)dag_bfs_bits,
                        hipFuncAttributeMaxDynamicSharedMemorySize, (int)lds);
    dag_bfs_bits<<<1, NN, lds, stream>>>(E, ET, rootbits, dagbits);

    expand_kernel<<<NN * NN / 4 / 256, 256, 0, stream>>>(dagbits, (float4*)d_out);
}